// Round 12
// baseline (4493.656 us; speedup 1.0000x reference)
//
#include <hip/hip_runtime.h>
#include <hip/hip_bf16.h>
#include <math.h>

// ---------------- problem constants ----------------
#define T_    512
#define B_    256
#define INP_  128
#define HID_  256
#define OUT_  64
#define DT_   0.1f
#define CPL_  0.1f

typedef __attribute__((ext_vector_type(8))) short          bf16x8;
typedef __attribute__((ext_vector_type(4))) float          f32x4;
typedef __attribute__((ext_vector_type(4))) unsigned short u16x4;

// ---------------- ws layout (ushort units, FRAGMENT-PERMUTED weights) ----------------
#define G_WH    0
#define G_WTAUH 1
#define G_WZR   2
#define G_WZI   3
#define G_WTAUZ 4
#define G_H2Z   5
#define G_Z2H   6
#define UH     458752   // 7*65536
#define UZ     491520
#define OH     524288
#define OZ     540672
#define NW_TOTAL 557056
#define BIAS_OFF_BYTES (NW_TOTAL * 2)
#define BT_H    0
#define BTAU_H  256
#define BH_TOT  512
#define BT_ZR   768
#define BT_ZI   1024
#define BTAU_Z  1280
#define BZR_TOT 1536
#define BZI_TOT 1792
#define BY      2048   // 64 floats
#define FLAGS_OFF_BYTES (BIAS_OFF_BYTES + 8448)   // 16 rg x (<=8) cg x 64B
#define STATE_OFF_BYTES (FLAGS_OFF_BYTES + 8192)
// state image (ROW-MAJOR fragment-friendly):
// [parity2][rg16] of { [state4][tile16][row16][col16] bf16 } = 32 KB per (parity,rg).
// Publishers scatter paired-u32 agent stores (r6/r8/r9/r11-proven pairing) into their
// tile's dense 512B slice; readers load 16B A-fragments directly as u64 pairs.

// fp32 -> bf16, round-to-nearest-even
__device__ __forceinline__ unsigned short f2bf(float f) {
    unsigned int u = __float_as_uint(f);
    u += 0x7fffu + ((u >> 16) & 1u);
    return (unsigned short)(u >> 16);
}

__device__ __forceinline__ float rcp_(float x) { return __builtin_amdgcn_rcpf(x); }
__device__ __forceinline__ float sigmoid_fast(float x) {
    return rcp_(1.0f + __expf(-x));
}
__device__ __forceinline__ float tanh_fast(float x) {
    return 1.0f - 2.0f * rcp_(__expf(2.0f * x) + 1.0f);
}

// ---------------- prep: weights fp32 -> bf16, fragment-permuted ----------------
__global__ void prep_weights(const float* __restrict__ Wh,   const float* __restrict__ Wtauh,
                             const float* __restrict__ Wzr,  const float* __restrict__ Wzi,
                             const float* __restrict__ Wtauz,const float* __restrict__ h2z,
                             const float* __restrict__ z2h,  const float* __restrict__ Uh,
                             const float* __restrict__ Uz,   const float* __restrict__ oh,
                             const float* __restrict__ oz,   unsigned short* __restrict__ ws) {
    int fid = blockIdx.x * 256 + threadIdx.x;   // one 8-elem fragment per thread
    if (fid >= NW_TOTAL / 8) return;
    int o = fid * 8;
    const float* src;
    int row, col, K;
    float scale = 1.0f;
    if (o < UH) {                       // H region, K=256
        int g  = o >> 16;
        int r  = o & 65535;
        int T  = r >> 12;
        int r2 = r & 4095;
        int kt = r2 >> 9;
        int l  = (r2 & 511) >> 3;
        row = T * 16 + (l & 15);
        col = kt * 32 + (l >> 4) * 8;
        K = 256;
        if      (g == G_WH)    src = Wh;
        else if (g == G_WTAUH) src = Wtauh;
        else if (g == G_WZR)   src = Wzr;
        else if (g == G_WZI)   src = Wzi;
        else if (g == G_WTAUZ) src = Wtauz;
        else if (g == G_H2Z)   { src = h2z; scale = CPL_; }
        else                   { src = z2h; scale = CPL_; }
    } else if (o < OH) {                // U region, K=128
        int g  = (o - UH) >> 15;
        int r  = (o - UH) & 32767;
        int T  = r >> 11;
        int r2 = r & 2047;
        int kt = r2 >> 9;
        int l  = (r2 & 511) >> 3;
        row = T * 16 + (l & 15);
        col = kt * 32 + (l >> 4) * 8;
        K = 128;
        src = g ? Uz : Uh;
    } else {                            // OUT region, K=256
        int g  = (o - OH) >> 14;
        int r  = (o - OH) & 16383;
        int T  = r >> 12;
        int r2 = r & 4095;
        int kt = r2 >> 9;
        int l  = (r2 & 511) >> 3;
        row = T * 16 + (l & 15);
        col = kt * 32 + (l >> 4) * 8;
        K = 256;
        src = g ? oz : oh;
    }
    const float* p = src + (size_t)row * K + col;
    float4 v0 = *(const float4*)p;
    float4 v1 = *(const float4*)(p + 4);
    u16x4 a, b;
    a.x = f2bf(v0.x * scale); a.y = f2bf(v0.y * scale);
    a.z = f2bf(v0.z * scale); a.w = f2bf(v0.w * scale);
    b.x = f2bf(v1.x * scale); b.y = f2bf(v1.y * scale);
    b.z = f2bf(v1.z * scale); b.w = f2bf(v1.w * scale);
    *(u16x4*)(ws + o)     = a;
    *(u16x4*)(ws + o + 4) = b;
}

// ---------------- prep: folded biases (fp32) ----------------
__global__ void prep_bias(const float* __restrict__ Whb,  const float* __restrict__ Wtauhb,
                          const float* __restrict__ Uhb,  const float* __restrict__ bh,
                          const float* __restrict__ z2hb, const float* __restrict__ Wzrb,
                          const float* __restrict__ Wzib, const float* __restrict__ Wtauzb,
                          const float* __restrict__ Uzb,  const float* __restrict__ bzr,
                          const float* __restrict__ bzi,  const float* __restrict__ h2zb,
                          const float* __restrict__ ohb,  const float* __restrict__ ozb,
                          float* __restrict__ bias) {
    int n = threadIdx.x;
    if (n < 256) {
        bias[BT_H + n]    = Whb[n];
        bias[BTAU_H + n]  = Wtauhb[n];
        bias[BH_TOT + n]  = Uhb[n] + bh[n] + CPL_ * z2hb[n];
        bias[BT_ZR + n]   = Wzrb[n];
        bias[BT_ZI + n]   = Wzib[n];
        bias[BTAU_Z + n]  = Wtauzb[n];
        bias[BZR_TOT + n] = Uzb[n] + bzr[n] + CPL_ * h2zb[n];
        bias[BZI_TOT + n] = Uzb[n] + bzi[n] + CPL_ * h2zb[n];
        if (n < 64) bias[BY + n] = ohb[n] + ozb[n];
    }
}

// ---------------- prep: zero flags (8KB) + parity-0 state image (512KB) ----------------
// MUST run every launch (graph replay): S_0 = 0 and flags restart at 0.
__global__ void prep_zero(unsigned long long* __restrict__ p) {
    int i = blockIdx.x * 512 + threadIdx.x;
    if (i < 66560) p[i] = 0;    // (8192 + 524288) / 8
}

// Load weight fragments (fragment-permuted ws) into registers, once.
template<int NKT>
__device__ __forceinline__ void wload(bf16x8* w, const unsigned short* __restrict__ p, int loff) {
#pragma unroll
    for (int kt = 0; kt < NKT; ++kt) w[kt] = *(const bf16x8*)(p + kt * 512 + loff);
}

// GEMM with both operands in registers.
template<int NKT>
__device__ __forceinline__ void wgemm(const bf16x8* a, const bf16x8* w, f32x4& acc) {
#pragma unroll
    for (int kt = 0; kt < NKT; ++kt)
        acc = __builtin_amdgcn_mfma_f32_16x16x32_bf16(a[kt], w[kt], acc, 0, 0, 0);
}

// x A-fragment straight from global fp32
__device__ __forceinline__ bf16x8 loadXfrag(const float* __restrict__ xrow, int off) {
    float4 v0 = *(const float4*)(xrow + off);
    float4 v1 = *(const float4*)(xrow + off + 4);
    bf16x8 r;
    r[0] = (short)f2bf(v0.x); r[1] = (short)f2bf(v0.y);
    r[2] = (short)f2bf(v0.z); r[3] = (short)f2bf(v0.w);
    r[4] = (short)f2bf(v1.x); r[5] = (short)f2bf(v1.y);
    r[6] = (short)f2bf(v1.z); r[7] = (short)f2bf(v1.w);
    return r;
}

// Load 8 A-fragments (K=256) for one state DIRECTLY from the row-major image.
// st = image base of this state ([tile16][row16][col16] bf16).
// lane (m16,hi), kt: row m16, global cols kt*32+hi*8 .. +8
//  -> tile 2kt+(hi>>1), byte = tile*512 + m16*32 + (hi&1)*16.
__device__ __forceinline__ void loadAimg(const char* st, int m16, int hi, bf16x8* a) {
    const unsigned long long* b = (const unsigned long long*)
        (st + ((hi >> 1) * 512 + m16 * 32 + (hi & 1) * 16));
#pragma unroll
    for (int kt = 0; kt < 8; ++kt) {
        union { unsigned long long q[2]; bf16x8 v; } u;
        u.q[0] = __hip_atomic_load(b + kt * 128,     __ATOMIC_RELAXED,
                                   __HIP_MEMORY_SCOPE_AGENT);
        u.q[1] = __hip_atomic_load(b + kt * 128 + 1, __ATOMIC_RELAXED,
                                   __HIP_MEMORY_SCOPE_AGENT);
        a[kt] = u.v;
    }
}

// DIRECT row-major publish (no LDS): lane (col m16, rows 4hi..4hi+3) pairs with
// lane m16^1 via shfl (r6/r8/r9/r11-proven pairing) and scatters 2 u32 agent stores:
// rows hi*4 + odd*2 + {0,1}, col-pair (m16&~1). Covers the full 16x16 tile slice.
__device__ __forceinline__ void pub_rm(char* gslot, int m16, int hi, const float* v) {
    const int odd = m16 & 1;
    float oth[4];
#pragma unroll
    for (int j = 0; j < 4; ++j) oth[j] = __shfl_xor(v[j], 1);
#pragma unroll
    for (int k = 0; k < 2; ++k) {
        const int j = odd * 2 + k;
        const int r = hi * 4 + j;
        unsigned a = f2bf(v[j]), b = f2bf(oth[j]);
        unsigned u = odd ? (b | (a << 16)) : (a | (b << 16));
        __hip_atomic_store((unsigned*)(gslot + r * 32 + (m16 & ~1) * 2), u,
                           __ATOMIC_RELAXED, __HIP_MEMORY_SCOPE_AGENT);
    }
}

// Per-wave flag wait: lanes 0..3 poll the 4 peer flags (64B-padded) until all >= tgt.
__device__ __forceinline__ void waitflags(const unsigned* flg, int lane, unsigned tgt) {
    for (;;) {
        unsigned v = tgt;
        if (lane < 4)
            v = __hip_atomic_load(flg + lane * 16, __ATOMIC_RELAXED,
                                  __HIP_MEMORY_SCOPE_AGENT);
        if (__all((int)(v >= tgt))) break;
        __builtin_amdgcn_s_sleep(1);
    }
}

// ---------------- main recurrent kernel ----------------
// grid: 64 blocks; rg = bid&15 (XCD-local peers), cg = bid>>4 (0..3). 512 threads =
// 8 waves = 4 pairs; pair p = w>>1 owns tile tt = cg*4+p; role (w&1): 0 = h-path
// (+ y duty for tt<4, i.e. cg==0), 1 = z-path.
// Weights in VGPRs; A-fragments loaded DIRECTLY from the row-major global image;
// direct scatter publish (no LDS anywhere); one __syncthreads per step; flag sync (4 peers).
__launch_bounds__(512, 2)
__global__ void twistor_main(const float* __restrict__ x, unsigned short* __restrict__ ws,
                             float* __restrict__ y) {
    const int tid  = threadIdx.x;
    const int lane = tid & 63;
    const int w    = tid >> 6;          // 0..7
    const int pair = w >> 1;            // 0..3
    const int role = w & 1;             // 0 = h-wave, 1 = z-wave
    const int m16  = lane & 15;
    const int hi   = lane >> 4;
    const int loff = lane * 8;
    const int bid  = blockIdx.x;
    const int rg   = bid & 15;          // rowgroup 0..15  (peers share XCD)
    const int cg   = bid >> 4;          // colgroup 0..3
    const int tt   = cg * 4 + pair;     // this wave's col tile 0..15
    const int brow0 = rg * 16;
    const int n    = tt * 16 + m16;
    const float* bias = (const float*)((const char*)ws + BIAS_OFF_BYTES);
    unsigned* flg    = (unsigned*)((char*)ws + FLAGS_OFF_BYTES) + rg * 128;
    unsigned* myflag = flg + cg * 16;
    char* simg = (char*)ws + STATE_OFF_BYTES;

    // ---- per-wave weight registers ----
    bf16x8 wA[8], wB[8], wC[8], wU[4];
    bf16x8 wO[8], wO2[8];               // role 0 duty: OH, OZ (tt<4 only)
    bf16x8 wTZ[8];                      // role 1: WTAUZ
    if (role == 0) {
        wload<8>(wA, ws + G_WH    * 65536 + tt * 4096, loff);
        wload<8>(wB, ws + G_WTAUH * 65536 + tt * 4096, loff);
        wload<8>(wC, ws + G_Z2H   * 65536 + tt * 4096, loff);
        wload<4>(wU, ws + UH + tt * 2048, loff);
        if (tt < 4) {
            wload<8>(wO,  ws + OH + tt * 4096, loff);
            wload<8>(wO2, ws + OZ + tt * 4096, loff);
        }
    } else {
        wload<8>(wA, ws + G_WZR   * 65536 + tt * 4096, loff);
        wload<8>(wB, ws + G_WZI   * 65536 + tt * 4096, loff);
        wload<8>(wC, ws + G_H2Z   * 65536 + tt * 4096, loff);
        wload<4>(wU, ws + UZ + tt * 2048, loff);
        wload<8>(wTZ, ws + G_WTAUZ * 65536 + tt * 4096, loff);
    }

    const float bthh = bias[BT_H + n],    btauh = bias[BTAU_H + n], bht = bias[BH_TOT + n];
    const float btzr = bias[BT_ZR + n],   btzi  = bias[BT_ZI + n],  btauz = bias[BTAU_Z + n];
    const float bzrt = bias[BZR_TOT + n], bzit  = bias[BZI_TOT + n];
    const float by_  = (tt < 4 && role == 0) ? bias[BY + n] : 0.f;

    float s0_[4] = {0, 0, 0, 0};   // role 0: h ; role 1: zr
    float s1_[4] = {0, 0, 0, 0};   // role 1: zi

    for (int t = 0; t < T_; ++t) {
        // x fragments (flag-independent -> issue before spin, latency hidden)
        bf16x8 ax[4];
        {
            const float* xrow = x + ((size_t)t * B_ + brow0 + m16) * INP_;
#pragma unroll
            for (int kt = 0; kt < 4; ++kt) ax[kt] = loadXfrag(xrow, kt * 32 + hi * 8);
        }
        if (t > 0) waitflags(flg, lane, (unsigned)t);   // S_t published by all 4 peers

        const char* imgR = simg + (size_t)((t & 1) * 16 + rg) * 32768;
        char*       imgW = simg + (size_t)(((t + 1) & 1) * 16 + rg) * 32768;

        bf16x8 ah[8], azr[8];
        loadAimg(imgR,        m16, hi, ah);
        loadAimg(imgR + 8192, m16, hi, azr);

        if (role == 0) {
            // ---- h-path (+ y duty) ----
            const bool ydo = (tt < 4) && (t > 0);
            f32x4 a_y = {0.f, 0.f, 0.f, 0.f};
            if (ydo) { wgemm<8>(ah, wO, a_y); wgemm<8>(azr, wO2, a_y); }
            f32x4 a_th = {0.f, 0.f, 0.f, 0.f}, a_tau = {0.f, 0.f, 0.f, 0.f};
            f32x4 a_ch = {0.f, 0.f, 0.f, 0.f};
            wgemm<8>(ah,  wA, a_th);
            wgemm<8>(ah,  wB, a_tau);
            wgemm<8>(azr, wC, a_ch);
            wgemm<4>(ax,  wU, a_ch);
            if (ydo) {
#pragma unroll
                for (int j = 0; j < 4; ++j)
                    y[((size_t)(t - 1) * B_ + brow0 + hi * 4 + j) * OUT_ + n] =
                        a_y[j] + by_;
            }
            float hn[4];
#pragma unroll
            for (int j = 0; j < 4; ++j) {
                float th = fminf(fmaxf(sigmoid_fast(a_tau[j] + btauh), 0.01f), 1.0f) + 1e-6f;
                float dh = -s0_[j] + tanh_fast(a_th[j] + bthh) + a_ch[j] + bht;
                hn[j]    = s0_[j] + DT_ * dh * rcp_(th);
                s0_[j] = hn[j];
            }
            pub_rm(imgW + tt * 512, m16, hi, hn);                        // state 0 (h)
        } else {
            // ---- z-path ----
            bf16x8 azi[8], aza[8];
            loadAimg(imgR + 16384, m16, hi, azi);
            loadAimg(imgR + 24576, m16, hi, aza);
            f32x4 a_tzr = {0.f, 0.f, 0.f, 0.f}, a_tzi = {0.f, 0.f, 0.f, 0.f};
            f32x4 a_tz  = {0.f, 0.f, 0.f, 0.f}, a_cz  = {0.f, 0.f, 0.f, 0.f};
            wgemm<8>(azr, wA,  a_tzr);
            wgemm<8>(ah,  wC,  a_cz);
            wgemm<8>(azi, wB,  a_tzi);
            wgemm<8>(aza, wTZ, a_tz);
            wgemm<4>(ax,  wU,  a_cz);
            float zrn[4], zin[4], zan[4];
#pragma unroll
            for (int j = 0; j < 4; ++j) {
                float tz  = fminf(fmaxf(sigmoid_fast(a_tz[j] + btauz), 0.01f), 1.0f) + 1e-6f;
                float rtz = rcp_(tz);
                float dzr = -s0_[j] + tanh_fast(a_tzr[j] + btzr) + a_cz[j] + bzrt;
                float dzi = -s1_[j] + tanh_fast(a_tzi[j] + btzi) + a_cz[j] + bzit;
                zrn[j] = s0_[j] + DT_ * dzr * rtz;
                zin[j] = s1_[j] + DT_ * dzi * rtz;
                zan[j] = sqrtf(zrn[j] * zrn[j] + zin[j] * zin[j] + 1e-24f);
                s0_[j] = zrn[j]; s1_[j] = zin[j];
            }
            pub_rm(imgW + 8192  + tt * 512, m16, hi, zrn);               // state 1 (zr)
            pub_rm(imgW + 16384 + tt * 512, m16, hi, zin);               // state 2 (zi)
            pub_rm(imgW + 24576 + tt * 512, m16, hi, zan);               // state 3 (za)
        }
        __syncthreads();   // all 8 waves' publish stores drained (vmcnt 0 per wave)
        if (tid == 0)
            __hip_atomic_store(myflag, (unsigned)(t + 1), __ATOMIC_RELAXED,
                               __HIP_MEMORY_SCOPE_AGENT);
    }

    // final y_{T-1} from S_T (parity 0)
    if (role == 0 && tt < 4) {
        waitflags(flg, lane, (unsigned)T_);
        const char* imgR = simg + (size_t)((T_ & 1) * 16 + rg) * 32768;
        bf16x8 ah[8], azr[8];
        loadAimg(imgR,        m16, hi, ah);
        loadAimg(imgR + 8192, m16, hi, azr);
        f32x4 a_y = {0.f, 0.f, 0.f, 0.f};
        wgemm<8>(ah,  wO,  a_y);
        wgemm<8>(azr, wO2, a_y);
#pragma unroll
        for (int j = 0; j < 4; ++j)
            y[((size_t)(T_ - 1) * B_ + brow0 + hi * 4 + j) * OUT_ + n] = a_y[j] + by_;
    }
}

extern "C" void kernel_launch(void* const* d_in, const int* in_sizes, int n_in,
                              void* d_out, int out_size, void* d_ws, size_t ws_size,
                              hipStream_t stream) {
    const float* x = (const float*)d_in[0];
    unsigned short* ws = (unsigned short*)d_ws;
    float* bias = (float*)((char*)d_ws + BIAS_OFF_BYTES);

    prep_weights<<<(NW_TOTAL / 8 + 255) / 256, 256, 0, stream>>>(
        (const float*)d_in[1],  /* W_h_w */
        (const float*)d_in[5],  /* W_tau_h_w */
        (const float*)d_in[8],  /* W_z_real_w */
        (const float*)d_in[10], /* W_z_imag_w */
        (const float*)d_in[14], /* W_tau_z_w */
        (const float*)d_in[18], /* h2z_w */
        (const float*)d_in[20], /* z2h_w */
        (const float*)d_in[3],  /* U_h_w */
        (const float*)d_in[12], /* U_z_w */
        (const float*)d_in[22], /* out_h_w */
        (const float*)d_in[24], /* out_z_w */
        ws);
    prep_bias<<<1, 256, 0, stream>>>(
        (const float*)d_in[2],  /* W_h_b */
        (const float*)d_in[6],  /* W_tau_h_b */
        (const float*)d_in[4],  /* U_h_b */
        (const float*)d_in[7],  /* b_h */
        (const float*)d_in[21], /* z2h_b */
        (const float*)d_in[9],  /* W_z_real_b */
        (const float*)d_in[11], /* W_z_imag_b */
        (const float*)d_in[15], /* W_tau_z_b */
        (const float*)d_in[13], /* U_z_b */
        (const float*)d_in[16], /* b_z_real */
        (const float*)d_in[17], /* b_z_imag */
        (const float*)d_in[19], /* h2z_b */
        (const float*)d_in[23], /* out_h_b */
        (const float*)d_in[25], /* out_z_b */
        bias);
    prep_zero<<<130, 512, 0, stream>>>(
        (unsigned long long*)((char*)d_ws + FLAGS_OFF_BYTES));
    twistor_main<<<64, 512, 0, stream>>>(x, ws, (float*)d_out);
}

// Round 13
// 2902.711 us; speedup vs baseline: 1.5481x; 1.5481x over previous
//
#include <hip/hip_runtime.h>
#include <hip/hip_bf16.h>
#include <math.h>

// ---------------- problem constants ----------------
#define T_    512
#define B_    256
#define INP_  128
#define HID_  256
#define OUT_  64
#define DT_   0.1f
#define CPL_  0.1f

typedef __attribute__((ext_vector_type(8))) short          bf16x8;
typedef __attribute__((ext_vector_type(4))) float          f32x4;
typedef __attribute__((ext_vector_type(4))) unsigned short u16x4;

// ---------------- ws layout (ushort units, FRAGMENT-PERMUTED weights) ----------------
#define G_WH    0
#define G_WTAUH 1
#define G_WZR   2
#define G_WZI   3
#define G_WTAUZ 4
#define G_H2Z   5
#define G_Z2H   6
#define UH     458752   // 7*65536
#define UZ     491520
#define OH     524288
#define OZ     540672
#define NW_TOTAL 557056
#define BIAS_OFF_BYTES (NW_TOTAL * 2)
#define BT_H    0
#define BTAU_H  256
#define BH_TOT  512
#define BT_ZR   768
#define BT_ZI   1024
#define BTAU_Z  1280
#define BZR_TOT 1536
#define BZI_TOT 1792
#define BY      2048   // 64 floats
#define FLAGS_OFF_BYTES (BIAS_OFF_BYTES + 8448)   // 16 rg x 32 waveflags x 64B = 32 KB
#define STATE_OFF_BYTES (FLAGS_OFF_BYTES + 32768)
// state image (ROW-MAJOR fragment-friendly):
// [parity2][rg16] of { [state4][tile16][row16][col16] bf16 } = 32 KB per (parity,rg).
// Publishers scatter paired-u32 agent stores (r6/r8/r9/r11-proven pairing) into their
// tile's dense 512B slice; readers load 16B A-fragments directly as u64 pairs.
// Sync: PER-WAVE flags (tile,role) -- wave drains own stores (vmcnt0) then posts.

// fp32 -> bf16, round-to-nearest-even
__device__ __forceinline__ unsigned short f2bf(float f) {
    unsigned int u = __float_as_uint(f);
    u += 0x7fffu + ((u >> 16) & 1u);
    return (unsigned short)(u >> 16);
}

__device__ __forceinline__ float rcp_(float x) { return __builtin_amdgcn_rcpf(x); }
__device__ __forceinline__ float sigmoid_fast(float x) {
    return rcp_(1.0f + __expf(-x));
}
__device__ __forceinline__ float tanh_fast(float x) {
    return 1.0f - 2.0f * rcp_(__expf(2.0f * x) + 1.0f);
}

// ---------------- prep: weights fp32 -> bf16, fragment-permuted ----------------
__global__ void prep_weights(const float* __restrict__ Wh,   const float* __restrict__ Wtauh,
                             const float* __restrict__ Wzr,  const float* __restrict__ Wzi,
                             const float* __restrict__ Wtauz,const float* __restrict__ h2z,
                             const float* __restrict__ z2h,  const float* __restrict__ Uh,
                             const float* __restrict__ Uz,   const float* __restrict__ oh,
                             const float* __restrict__ oz,   unsigned short* __restrict__ ws) {
    int fid = blockIdx.x * 256 + threadIdx.x;   // one 8-elem fragment per thread
    if (fid >= NW_TOTAL / 8) return;
    int o = fid * 8;
    const float* src;
    int row, col, K;
    float scale = 1.0f;
    if (o < UH) {                       // H region, K=256
        int g  = o >> 16;
        int r  = o & 65535;
        int T  = r >> 12;
        int r2 = r & 4095;
        int kt = r2 >> 9;
        int l  = (r2 & 511) >> 3;
        row = T * 16 + (l & 15);
        col = kt * 32 + (l >> 4) * 8;
        K = 256;
        if      (g == G_WH)    src = Wh;
        else if (g == G_WTAUH) src = Wtauh;
        else if (g == G_WZR)   src = Wzr;
        else if (g == G_WZI)   src = Wzi;
        else if (g == G_WTAUZ) src = Wtauz;
        else if (g == G_H2Z)   { src = h2z; scale = CPL_; }
        else                   { src = z2h; scale = CPL_; }
    } else if (o < OH) {                // U region, K=128
        int g  = (o - UH) >> 15;
        int r  = (o - UH) & 32767;
        int T  = r >> 11;
        int r2 = r & 2047;
        int kt = r2 >> 9;
        int l  = (r2 & 511) >> 3;
        row = T * 16 + (l & 15);
        col = kt * 32 + (l >> 4) * 8;
        K = 128;
        src = g ? Uz : Uh;
    } else {                            // OUT region, K=256
        int g  = (o - OH) >> 14;
        int r  = (o - OH) & 16383;
        int T  = r >> 12;
        int r2 = r & 4095;
        int kt = r2 >> 9;
        int l  = (r2 & 511) >> 3;
        row = T * 16 + (l & 15);
        col = kt * 32 + (l >> 4) * 8;
        K = 256;
        src = g ? oz : oh;
    }
    const float* p = src + (size_t)row * K + col;
    float4 v0 = *(const float4*)p;
    float4 v1 = *(const float4*)(p + 4);
    u16x4 a, b;
    a.x = f2bf(v0.x * scale); a.y = f2bf(v0.y * scale);
    a.z = f2bf(v0.z * scale); a.w = f2bf(v0.w * scale);
    b.x = f2bf(v1.x * scale); b.y = f2bf(v1.y * scale);
    b.z = f2bf(v1.z * scale); b.w = f2bf(v1.w * scale);
    *(u16x4*)(ws + o)     = a;
    *(u16x4*)(ws + o + 4) = b;
}

// ---------------- prep: folded biases (fp32) ----------------
__global__ void prep_bias(const float* __restrict__ Whb,  const float* __restrict__ Wtauhb,
                          const float* __restrict__ Uhb,  const float* __restrict__ bh,
                          const float* __restrict__ z2hb, const float* __restrict__ Wzrb,
                          const float* __restrict__ Wzib, const float* __restrict__ Wtauzb,
                          const float* __restrict__ Uzb,  const float* __restrict__ bzr,
                          const float* __restrict__ bzi,  const float* __restrict__ h2zb,
                          const float* __restrict__ ohb,  const float* __restrict__ ozb,
                          float* __restrict__ bias) {
    int n = threadIdx.x;
    if (n < 256) {
        bias[BT_H + n]    = Whb[n];
        bias[BTAU_H + n]  = Wtauhb[n];
        bias[BH_TOT + n]  = Uhb[n] + bh[n] + CPL_ * z2hb[n];
        bias[BT_ZR + n]   = Wzrb[n];
        bias[BT_ZI + n]   = Wzib[n];
        bias[BTAU_Z + n]  = Wtauzb[n];
        bias[BZR_TOT + n] = Uzb[n] + bzr[n] + CPL_ * h2zb[n];
        bias[BZI_TOT + n] = Uzb[n] + bzi[n] + CPL_ * h2zb[n];
        if (n < 64) bias[BY + n] = ohb[n] + ozb[n];
    }
}

// ---------------- prep: zero flags (32KB) + parity-0 state image (512KB) ----------------
// MUST run every launch (graph replay): S_0 = 0 and flags restart at 0.
__global__ void prep_zero(unsigned long long* __restrict__ p) {
    int i = blockIdx.x * 512 + threadIdx.x;
    if (i < 69632) p[i] = 0;    // (32768 + 524288) / 8
}

// Load weight fragments (fragment-permuted ws) into registers, once.
template<int NKT>
__device__ __forceinline__ void wload(bf16x8* w, const unsigned short* __restrict__ p, int loff) {
#pragma unroll
    for (int kt = 0; kt < NKT; ++kt) w[kt] = *(const bf16x8*)(p + kt * 512 + loff);
}

// GEMM with both operands in registers.
template<int NKT>
__device__ __forceinline__ void wgemm(const bf16x8* a, const bf16x8* w, f32x4& acc) {
#pragma unroll
    for (int kt = 0; kt < NKT; ++kt)
        acc = __builtin_amdgcn_mfma_f32_16x16x32_bf16(a[kt], w[kt], acc, 0, 0, 0);
}

// x A-fragment straight from global fp32
__device__ __forceinline__ bf16x8 loadXfrag(const float* __restrict__ xrow, int off) {
    float4 v0 = *(const float4*)(xrow + off);
    float4 v1 = *(const float4*)(xrow + off + 4);
    bf16x8 r;
    r[0] = (short)f2bf(v0.x); r[1] = (short)f2bf(v0.y);
    r[2] = (short)f2bf(v0.z); r[3] = (short)f2bf(v0.w);
    r[4] = (short)f2bf(v1.x); r[5] = (short)f2bf(v1.y);
    r[6] = (short)f2bf(v1.z); r[7] = (short)f2bf(v1.w);
    return r;
}

// Load 8 A-fragments (K=256) for one state DIRECTLY from the row-major image.
// st = image base of this state ([tile16][row16][col16] bf16).
// lane (m16,hi), kt: row m16, global cols kt*32+hi*8 .. +8
//  -> tile 2kt+(hi>>1), byte = tile*512 + m16*32 + (hi&1)*16.
__device__ __forceinline__ void loadAimg(const char* st, int m16, int hi, bf16x8* a) {
    const unsigned long long* b = (const unsigned long long*)
        (st + ((hi >> 1) * 512 + m16 * 32 + (hi & 1) * 16));
#pragma unroll
    for (int kt = 0; kt < 8; ++kt) {
        union { unsigned long long q[2]; bf16x8 v; } u;
        u.q[0] = __hip_atomic_load(b + kt * 128,     __ATOMIC_RELAXED,
                                   __HIP_MEMORY_SCOPE_AGENT);
        u.q[1] = __hip_atomic_load(b + kt * 128 + 1, __ATOMIC_RELAXED,
                                   __HIP_MEMORY_SCOPE_AGENT);
        a[kt] = u.v;
    }
}

// DIRECT row-major publish (no LDS): lane (col m16, rows 4hi..4hi+3) pairs with
// lane m16^1 via shfl (r6/r8/r9/r11-proven pairing) and scatters 2 u32 agent stores:
// rows hi*4 + odd*2 + {0,1}, col-pair (m16&~1). Covers the full 16x16 tile slice.
__device__ __forceinline__ void pub_rm(char* gslot, int m16, int hi, const float* v) {
    const int odd = m16 & 1;
    float oth[4];
#pragma unroll
    for (int j = 0; j < 4; ++j) oth[j] = __shfl_xor(v[j], 1);
#pragma unroll
    for (int k = 0; k < 2; ++k) {
        const int j = odd * 2 + k;
        const int r = hi * 4 + j;
        unsigned a = f2bf(v[j]), b = f2bf(oth[j]);
        unsigned u = odd ? (b | (a << 16)) : (a | (b << 16));
        __hip_atomic_store((unsigned*)(gslot + r * 32 + (m16 & ~1) * 2), u,
                           __ATOMIC_RELAXED, __HIP_MEMORY_SCOPE_AGENT);
    }
}

// Per-wave flag wait: lanes 0..31 poll the 32 wave-flags (64B-padded) until all >= tgt.
__device__ __forceinline__ void waitflags(const unsigned* flg, int lane, unsigned tgt) {
    for (;;) {
        unsigned v = tgt;
        if (lane < 32)
            v = __hip_atomic_load(flg + lane * 16, __ATOMIC_RELAXED,
                                  __HIP_MEMORY_SCOPE_AGENT);
        if (__all((int)(v >= tgt))) break;
        __builtin_amdgcn_s_sleep(1);
    }
}

// Per-wave flag post: drain THIS WAVE's outstanding vm ops, then post.
__device__ __forceinline__ void postflag(unsigned* myflag, int lane, unsigned val) {
    asm volatile("s_waitcnt vmcnt(0)" ::: "memory");
    if (lane == 0)
        __hip_atomic_store(myflag, val, __ATOMIC_RELAXED, __HIP_MEMORY_SCOPE_AGENT);
}

// ---------------- main recurrent kernel ----------------
// grid: 128 blocks; rg = bid&15 (XCD-local peers), cg = bid>>4. 256 threads = 4 waves:
// wave w: tile tt = 2*cg + (w>>1), role (w&1): 0 = h-path (+ full y duty), 1 = z-path.
// Weights in VGPRs; A-fragments loaded DIRECTLY from the row-major global image;
// direct scatter publish (no LDS anywhere); NO barriers -- per-wave flag sync.
__launch_bounds__(256, 1)
__global__ void twistor_main(const float* __restrict__ x, unsigned short* __restrict__ ws,
                             float* __restrict__ y) {
    const int tid  = threadIdx.x;
    const int lane = tid & 63;
    const int w    = tid >> 6;          // 0..3
    const int half = w >> 1;            // tile within block: 0/1
    const int role = w & 1;             // 0 = h-wave, 1 = z-wave
    const int m16  = lane & 15;
    const int hi   = lane >> 4;
    const int loff = lane * 8;
    const int bid  = blockIdx.x;
    const int rg   = bid & 15;          // rowgroup 0..15  (peers share XCD)
    const int cg   = bid >> 4;          // colgroup 0..7
    const int tt   = cg * 2 + half;     // this wave's col tile 0..15
    const int brow0 = rg * 16;
    const int n    = tt * 16 + m16;
    const float* bias = (const float*)((const char*)ws + BIAS_OFF_BYTES);
    unsigned* flg    = (unsigned*)((char*)ws + FLAGS_OFF_BYTES) + rg * 512;
    unsigned* myflag = flg + (tt * 2 + role) * 16;
    char* simg = (char*)ws + STATE_OFF_BYTES;

    // ---- per-wave weight registers ----
    bf16x8 wA[8], wB[8], wC[8], wU[4];
    bf16x8 wO[8], wO2[8];               // role 0 duty: OH, OZ
    bf16x8 wTZ[8];                      // role 1: WTAUZ
    if (role == 0) {
        wload<8>(wA, ws + G_WH    * 65536 + tt * 4096, loff);
        wload<8>(wB, ws + G_WTAUH * 65536 + tt * 4096, loff);
        wload<8>(wC, ws + G_Z2H   * 65536 + tt * 4096, loff);
        wload<4>(wU, ws + UH + tt * 2048, loff);
        if (tt < 4) {
            wload<8>(wO,  ws + OH + tt * 4096, loff);
            wload<8>(wO2, ws + OZ + tt * 4096, loff);
        }
    } else {
        wload<8>(wA, ws + G_WZR   * 65536 + tt * 4096, loff);
        wload<8>(wB, ws + G_WZI   * 65536 + tt * 4096, loff);
        wload<8>(wC, ws + G_H2Z   * 65536 + tt * 4096, loff);
        wload<4>(wU, ws + UZ + tt * 2048, loff);
        wload<8>(wTZ, ws + G_WTAUZ * 65536 + tt * 4096, loff);
    }

    const float bthh = bias[BT_H + n],    btauh = bias[BTAU_H + n], bht = bias[BH_TOT + n];
    const float btzr = bias[BT_ZR + n],   btzi  = bias[BT_ZI + n],  btauz = bias[BTAU_Z + n];
    const float bzrt = bias[BZR_TOT + n], bzit  = bias[BZI_TOT + n];
    const float by_  = (tt < 4 && role == 0) ? bias[BY + n] : 0.f;

    float s0_[4] = {0, 0, 0, 0};   // role 0: h ; role 1: zr
    float s1_[4] = {0, 0, 0, 0};   // role 1: zi

    for (int t = 0; t < T_; ++t) {
        // x fragments (flag-independent -> issue before spin, latency hidden)
        bf16x8 ax[4];
        {
            const float* xrow = x + ((size_t)t * B_ + brow0 + m16) * INP_;
#pragma unroll
            for (int kt = 0; kt < 4; ++kt) ax[kt] = loadXfrag(xrow, kt * 32 + hi * 8);
        }
        if (t > 0) waitflags(flg, lane, (unsigned)t);   // S_t published by all 32 waves

        const char* imgR = simg + (size_t)((t & 1) * 16 + rg) * 32768;
        char*       imgW = simg + (size_t)(((t + 1) & 1) * 16 + rg) * 32768;

        bf16x8 ah[8], azr[8];
        loadAimg(imgR,        m16, hi, ah);
        loadAimg(imgR + 8192, m16, hi, azr);

        if (role == 0) {
            // ---- h-path (+ y duty) ----
            const bool ydo = (tt < 4) && (t > 0);
            f32x4 a_y = {0.f, 0.f, 0.f, 0.f};
            if (ydo) { wgemm<8>(ah, wO, a_y); wgemm<8>(azr, wO2, a_y); }
            f32x4 a_th = {0.f, 0.f, 0.f, 0.f}, a_tau = {0.f, 0.f, 0.f, 0.f};
            f32x4 a_ch = {0.f, 0.f, 0.f, 0.f};
            wgemm<8>(ah,  wA, a_th);
            wgemm<8>(ah,  wB, a_tau);
            wgemm<8>(azr, wC, a_ch);
            wgemm<4>(ax,  wU, a_ch);
            if (ydo) {
#pragma unroll
                for (int j = 0; j < 4; ++j)
                    y[((size_t)(t - 1) * B_ + brow0 + hi * 4 + j) * OUT_ + n] =
                        a_y[j] + by_;
            }
            float hn[4];
#pragma unroll
            for (int j = 0; j < 4; ++j) {
                float th = fminf(fmaxf(sigmoid_fast(a_tau[j] + btauh), 0.01f), 1.0f) + 1e-6f;
                float dh = -s0_[j] + tanh_fast(a_th[j] + bthh) + a_ch[j] + bht;
                hn[j]    = s0_[j] + DT_ * dh * rcp_(th);
                s0_[j] = hn[j];
            }
            pub_rm(imgW + tt * 512, m16, hi, hn);                        // state 0 (h)
        } else {
            // ---- z-path ----
            bf16x8 azi[8], aza[8];
            loadAimg(imgR + 16384, m16, hi, azi);
            loadAimg(imgR + 24576, m16, hi, aza);
            f32x4 a_tzr = {0.f, 0.f, 0.f, 0.f}, a_tzi = {0.f, 0.f, 0.f, 0.f};
            f32x4 a_tz  = {0.f, 0.f, 0.f, 0.f}, a_cz  = {0.f, 0.f, 0.f, 0.f};
            wgemm<8>(azr, wA,  a_tzr);
            wgemm<8>(ah,  wC,  a_cz);
            wgemm<8>(azi, wB,  a_tzi);
            wgemm<8>(aza, wTZ, a_tz);
            wgemm<4>(ax,  wU,  a_cz);
            float zrn[4], zin[4], zan[4];
#pragma unroll
            for (int j = 0; j < 4; ++j) {
                float tz  = fminf(fmaxf(sigmoid_fast(a_tz[j] + btauz), 0.01f), 1.0f) + 1e-6f;
                float rtz = rcp_(tz);
                float dzr = -s0_[j] + tanh_fast(a_tzr[j] + btzr) + a_cz[j] + bzrt;
                float dzi = -s1_[j] + tanh_fast(a_tzi[j] + btzi) + a_cz[j] + bzit;
                zrn[j] = s0_[j] + DT_ * dzr * rtz;
                zin[j] = s1_[j] + DT_ * dzi * rtz;
                zan[j] = sqrtf(zrn[j] * zrn[j] + zin[j] * zin[j] + 1e-24f);
                s0_[j] = zrn[j]; s1_[j] = zin[j];
            }
            pub_rm(imgW + 8192  + tt * 512, m16, hi, zrn);               // state 1 (zr)
            pub_rm(imgW + 16384 + tt * 512, m16, hi, zin);               // state 2 (zi)
            pub_rm(imgW + 24576 + tt * 512, m16, hi, zan);               // state 3 (za)
        }
        // per-wave: drain own stores (incl. y), post own flag. No barrier.
        postflag(myflag, lane, (unsigned)(t + 1));
    }

    // final y_{T-1} from S_T (parity 0)
    if (role == 0 && tt < 4) {
        waitflags(flg, lane, (unsigned)T_);
        const char* imgR = simg + (size_t)((T_ & 1) * 16 + rg) * 32768;
        bf16x8 ah[8], azr[8];
        loadAimg(imgR,        m16, hi, ah);
        loadAimg(imgR + 8192, m16, hi, azr);
        f32x4 a_y = {0.f, 0.f, 0.f, 0.f};
        wgemm<8>(ah,  wO,  a_y);
        wgemm<8>(azr, wO2, a_y);
#pragma unroll
        for (int j = 0; j < 4; ++j)
            y[((size_t)(T_ - 1) * B_ + brow0 + hi * 4 + j) * OUT_ + n] = a_y[j] + by_;
    }
}

extern "C" void kernel_launch(void* const* d_in, const int* in_sizes, int n_in,
                              void* d_out, int out_size, void* d_ws, size_t ws_size,
                              hipStream_t stream) {
    const float* x = (const float*)d_in[0];
    unsigned short* ws = (unsigned short*)d_ws;
    float* bias = (float*)((char*)d_ws + BIAS_OFF_BYTES);

    prep_weights<<<(NW_TOTAL / 8 + 255) / 256, 256, 0, stream>>>(
        (const float*)d_in[1],  /* W_h_w */
        (const float*)d_in[5],  /* W_tau_h_w */
        (const float*)d_in[8],  /* W_z_real_w */
        (const float*)d_in[10], /* W_z_imag_w */
        (const float*)d_in[14], /* W_tau_z_w */
        (const float*)d_in[18], /* h2z_w */
        (const float*)d_in[20], /* z2h_w */
        (const float*)d_in[3],  /* U_h_w */
        (const float*)d_in[12], /* U_z_w */
        (const float*)d_in[22], /* out_h_w */
        (const float*)d_in[24], /* out_z_w */
        ws);
    prep_bias<<<1, 256, 0, stream>>>(
        (const float*)d_in[2],  /* W_h_b */
        (const float*)d_in[6],  /* W_tau_h_b */
        (const float*)d_in[4],  /* U_h_b */
        (const float*)d_in[7],  /* b_h */
        (const float*)d_in[21], /* z2h_b */
        (const float*)d_in[9],  /* W_z_real_b */
        (const float*)d_in[11], /* W_z_imag_b */
        (const float*)d_in[15], /* W_tau_z_b */
        (const float*)d_in[13], /* U_z_b */
        (const float*)d_in[16], /* b_z_real */
        (const float*)d_in[17], /* b_z_imag */
        (const float*)d_in[19], /* h2z_b */
        (const float*)d_in[23], /* out_h_b */
        (const float*)d_in[25], /* out_z_b */
        bias);
    prep_zero<<<136, 512, 0, stream>>>(
        (unsigned long long*)((char*)d_ws + FLAGS_OFF_BYTES));
    twistor_main<<<128, 256, 0, stream>>>(x, ws, (float*)d_out);
}

// Round 14
// 2656.929 us; speedup vs baseline: 1.6913x; 1.0925x over previous
//
#include <hip/hip_runtime.h>
#include <hip/hip_bf16.h>
#include <math.h>

// ---------------- problem constants ----------------
#define T_    512
#define B_    256
#define INP_  128
#define HID_  256
#define OUT_  64
#define DT_   0.1f
#define CPL_  0.1f

typedef __attribute__((ext_vector_type(8))) short          bf16x8;
typedef __attribute__((ext_vector_type(4))) float          f32x4;
typedef __attribute__((ext_vector_type(4))) unsigned short u16x4;

// ---------------- ws layout (ushort units, FRAGMENT-PERMUTED weights) ----------------
#define G_WH    0
#define G_WTAUH 1
#define G_WZR   2
#define G_WZI   3
#define G_WTAUZ 4
#define G_H2Z   5
#define G_Z2H   6
#define UH     458752   // 7*65536
#define UZ     491520
#define OH     524288
#define OZ     540672
#define NW_TOTAL 557056
#define BIAS_OFF_BYTES (NW_TOTAL * 2)
#define BT_H    0
#define BTAU_H  256
#define BH_TOT  512
#define BT_ZR   768
#define BT_ZI   1024
#define BTAU_Z  1280
#define BZR_TOT 1536
#define BZI_TOT 1792
#define BY      2048   // 64 floats
// Region after biases (BIAS+8448):
//  POLL mode:  [slot 0..512][rg16][32KB] write-once state slots (poison-filled)
//  FLAG mode (fallback): 32KB wave-flags + [parity2][rg16][32KB] image (r13)
#define REGION_OFF_BYTES (BIAS_OFF_BYTES + 8448)
#define POISON32 0x7FC07FC0u
#define POISON64 0x7FC07FC07FC07FC0ull
// slot layout: [state4][tile16][row16][col16] bf16 = 32 KB per (t,rg).

// fp32 -> bf16, round-to-nearest-even
__device__ __forceinline__ unsigned short f2bf(float f) {
    unsigned int u = __float_as_uint(f);
    u += 0x7fffu + ((u >> 16) & 1u);
    return (unsigned short)(u >> 16);
}

__device__ __forceinline__ float rcp_(float x) { return __builtin_amdgcn_rcpf(x); }
__device__ __forceinline__ float sigmoid_fast(float x) {
    return rcp_(1.0f + __expf(-x));
}
__device__ __forceinline__ float tanh_fast(float x) {
    return 1.0f - 2.0f * rcp_(__expf(2.0f * x) + 1.0f);
}

#define AGLD(p) __hip_atomic_load((p), __ATOMIC_RELAXED, __HIP_MEMORY_SCOPE_AGENT)
#define AGST(p, v) __hip_atomic_store((p), (v), __ATOMIC_RELAXED, __HIP_MEMORY_SCOPE_AGENT)

// ---------------- prep: weights fp32 -> bf16, fragment-permuted ----------------
__global__ void prep_weights(const float* __restrict__ Wh,   const float* __restrict__ Wtauh,
                             const float* __restrict__ Wzr,  const float* __restrict__ Wzi,
                             const float* __restrict__ Wtauz,const float* __restrict__ h2z,
                             const float* __restrict__ z2h,  const float* __restrict__ Uh,
                             const float* __restrict__ Uz,   const float* __restrict__ oh,
                             const float* __restrict__ oz,   unsigned short* __restrict__ ws) {
    int fid = blockIdx.x * 256 + threadIdx.x;   // one 8-elem fragment per thread
    if (fid >= NW_TOTAL / 8) return;
    int o = fid * 8;
    const float* src;
    int row, col, K;
    float scale = 1.0f;
    if (o < UH) {                       // H region, K=256
        int g  = o >> 16;
        int r  = o & 65535;
        int T  = r >> 12;
        int r2 = r & 4095;
        int kt = r2 >> 9;
        int l  = (r2 & 511) >> 3;
        row = T * 16 + (l & 15);
        col = kt * 32 + (l >> 4) * 8;
        K = 256;
        if      (g == G_WH)    src = Wh;
        else if (g == G_WTAUH) src = Wtauh;
        else if (g == G_WZR)   src = Wzr;
        else if (g == G_WZI)   src = Wzi;
        else if (g == G_WTAUZ) src = Wtauz;
        else if (g == G_H2Z)   { src = h2z; scale = CPL_; }
        else                   { src = z2h; scale = CPL_; }
    } else if (o < OH) {                // U region, K=128
        int g  = (o - UH) >> 15;
        int r  = (o - UH) & 32767;
        int T  = r >> 11;
        int r2 = r & 2047;
        int kt = r2 >> 9;
        int l  = (r2 & 511) >> 3;
        row = T * 16 + (l & 15);
        col = kt * 32 + (l >> 4) * 8;
        K = 128;
        src = g ? Uz : Uh;
    } else {                            // OUT region, K=256
        int g  = (o - OH) >> 14;
        int r  = (o - OH) & 16383;
        int T  = r >> 12;
        int r2 = r & 4095;
        int kt = r2 >> 9;
        int l  = (r2 & 511) >> 3;
        row = T * 16 + (l & 15);
        col = kt * 32 + (l >> 4) * 8;
        K = 256;
        src = g ? oz : oh;
    }
    const float* p = src + (size_t)row * K + col;
    float4 v0 = *(const float4*)p;
    float4 v1 = *(const float4*)(p + 4);
    u16x4 a, b;
    a.x = f2bf(v0.x * scale); a.y = f2bf(v0.y * scale);
    a.z = f2bf(v0.z * scale); a.w = f2bf(v0.w * scale);
    b.x = f2bf(v1.x * scale); b.y = f2bf(v1.y * scale);
    b.z = f2bf(v1.z * scale); b.w = f2bf(v1.w * scale);
    *(u16x4*)(ws + o)     = a;
    *(u16x4*)(ws + o + 4) = b;
}

// ---------------- prep: folded biases (fp32) ----------------
__global__ void prep_bias(const float* __restrict__ Whb,  const float* __restrict__ Wtauhb,
                          const float* __restrict__ Uhb,  const float* __restrict__ bh,
                          const float* __restrict__ z2hb, const float* __restrict__ Wzrb,
                          const float* __restrict__ Wzib, const float* __restrict__ Wtauzb,
                          const float* __restrict__ Uzb,  const float* __restrict__ bzr,
                          const float* __restrict__ bzi,  const float* __restrict__ h2zb,
                          const float* __restrict__ ohb,  const float* __restrict__ ozb,
                          float* __restrict__ bias) {
    int n = threadIdx.x;
    if (n < 256) {
        bias[BT_H + n]    = Whb[n];
        bias[BTAU_H + n]  = Wtauhb[n];
        bias[BH_TOT + n]  = Uhb[n] + bh[n] + CPL_ * z2hb[n];
        bias[BT_ZR + n]   = Wzrb[n];
        bias[BT_ZI + n]   = Wzib[n];
        bias[BTAU_Z + n]  = Wtauzb[n];
        bias[BZR_TOT + n] = Uzb[n] + bzr[n] + CPL_ * h2zb[n];
        bias[BZI_TOT + n] = Uzb[n] + bzi[n] + CPL_ * h2zb[n];
        if (n < 64) bias[BY + n] = ohb[n] + ozb[n];
    }
}

// ---------------- prep (POLL): zero slot 0, poison slots 1..512 ----------------
// MUST run every launch (graph replay).
__global__ void prep_poison(unsigned long long* __restrict__ p) {
    const size_t nslot0 = 16ull * 4096;          // S_0 (zeros)
    const size_t ntot   = 513ull * 16 * 4096;    // all slots, u64 units
    for (size_t i = (size_t)blockIdx.x * 512 + threadIdx.x; i < ntot;
         i += (size_t)gridDim.x * 512)
        p[i] = (i < nslot0) ? 0ull : POISON64;
}

// ---------------- prep (FLAG fallback): zero flags (32KB) + parity image (1MB) -------
__global__ void prep_zero(unsigned long long* __restrict__ p) {
    int i = blockIdx.x * 512 + threadIdx.x;
    if (i < 135168) p[i] = 0;    // (32768 + 2*16*32768) / 8
}

// Load weight fragments (fragment-permuted ws) into registers, once.
template<int NKT>
__device__ __forceinline__ void wload(bf16x8* w, const unsigned short* __restrict__ p, int loff) {
#pragma unroll
    for (int kt = 0; kt < NKT; ++kt) w[kt] = *(const bf16x8*)(p + kt * 512 + loff);
}

// GEMM with both operands in registers.
template<int NKT>
__device__ __forceinline__ void wgemm(const bf16x8* a, const bf16x8* w, f32x4& acc) {
#pragma unroll
    for (int kt = 0; kt < NKT; ++kt)
        acc = __builtin_amdgcn_mfma_f32_16x16x32_bf16(a[kt], w[kt], acc, 0, 0, 0);
}

// x A-fragment straight from global fp32
__device__ __forceinline__ bf16x8 loadXfrag(const float* __restrict__ xrow, int off) {
    float4 v0 = *(const float4*)(xrow + off);
    float4 v1 = *(const float4*)(xrow + off + 4);
    bf16x8 r;
    r[0] = (short)f2bf(v0.x); r[1] = (short)f2bf(v0.y);
    r[2] = (short)f2bf(v0.z); r[3] = (short)f2bf(v0.w);
    r[4] = (short)f2bf(v1.x); r[5] = (short)f2bf(v1.y);
    r[6] = (short)f2bf(v1.z); r[7] = (short)f2bf(v1.w);
    return r;
}

// Plain A-fragment load from a ready slot (final-y fast path / flag kernel).
__device__ __forceinline__ void loadAimg(const char* st, int m16, int hi, bf16x8* a) {
    const unsigned long long* b = (const unsigned long long*)
        (st + ((hi >> 1) * 512 + m16 * 32 + (hi & 1) * 16));
#pragma unroll
    for (int kt = 0; kt < 8; ++kt) {
        union { unsigned long long q[2]; bf16x8 v; } u;
        u.q[0] = AGLD(b + kt * 128);
        u.q[1] = AGLD(b + kt * 128 + 1);
        a[kt] = u.v;
    }
}

__device__ __forceinline__ int chkq(unsigned long long q) {
    return ((unsigned)q == POISON32) || ((unsigned)(q >> 32) == POISON32);
}

// Poll-load 2 states' A-fragments (h, zr) until poison-free. Data IS the flag.
__device__ __forceinline__ void pollA2(const char* slot, int m16, int hi,
                                       bf16x8* a0, bf16x8* a1) {
    const size_t off = (size_t)((hi >> 1) * 512 + m16 * 32 + (hi & 1) * 16);
    const unsigned long long* b0 = (const unsigned long long*)(slot + off);
    const unsigned long long* b1 = (const unsigned long long*)(slot + 8192 + off);
    unsigned long long q0[16], q1[16];
    for (;;) {
        int dirty = 0;
#pragma unroll
        for (int kt = 0; kt < 8; ++kt) {
            q0[2 * kt]     = AGLD(b0 + kt * 128);
            q0[2 * kt + 1] = AGLD(b0 + kt * 128 + 1);
            q1[2 * kt]     = AGLD(b1 + kt * 128);
            q1[2 * kt + 1] = AGLD(b1 + kt * 128 + 1);
        }
#pragma unroll
        for (int i = 0; i < 16; ++i) dirty |= chkq(q0[i]) | chkq(q1[i]);
        if (!__any(dirty)) break;
        __builtin_amdgcn_s_sleep(1);
    }
#pragma unroll
    for (int kt = 0; kt < 8; ++kt) {
        union { unsigned long long q[2]; bf16x8 v; } u;
        u.q[0] = q0[2 * kt]; u.q[1] = q0[2 * kt + 1]; a0[kt] = u.v;
        u.q[0] = q1[2 * kt]; u.q[1] = q1[2 * kt + 1]; a1[kt] = u.v;
    }
}

// Poll-load all 4 states' A-fragments until poison-free.
__device__ __forceinline__ void pollA4(const char* slot, int m16, int hi,
                                       bf16x8* a0, bf16x8* a1, bf16x8* a2, bf16x8* a3) {
    const size_t off = (size_t)((hi >> 1) * 512 + m16 * 32 + (hi & 1) * 16);
    const unsigned long long* b0 = (const unsigned long long*)(slot + off);
    const unsigned long long* b1 = (const unsigned long long*)(slot + 8192 + off);
    const unsigned long long* b2 = (const unsigned long long*)(slot + 16384 + off);
    const unsigned long long* b3 = (const unsigned long long*)(slot + 24576 + off);
    unsigned long long q0[16], q1[16], q2[16], q3[16];
    for (;;) {
        int dirty = 0;
#pragma unroll
        for (int kt = 0; kt < 8; ++kt) {
            q0[2 * kt]     = AGLD(b0 + kt * 128);
            q0[2 * kt + 1] = AGLD(b0 + kt * 128 + 1);
            q1[2 * kt]     = AGLD(b1 + kt * 128);
            q1[2 * kt + 1] = AGLD(b1 + kt * 128 + 1);
            q2[2 * kt]     = AGLD(b2 + kt * 128);
            q2[2 * kt + 1] = AGLD(b2 + kt * 128 + 1);
            q3[2 * kt]     = AGLD(b3 + kt * 128);
            q3[2 * kt + 1] = AGLD(b3 + kt * 128 + 1);
        }
#pragma unroll
        for (int i = 0; i < 16; ++i)
            dirty |= chkq(q0[i]) | chkq(q1[i]) | chkq(q2[i]) | chkq(q3[i]);
        if (!__any(dirty)) break;
        __builtin_amdgcn_s_sleep(1);
    }
#pragma unroll
    for (int kt = 0; kt < 8; ++kt) {
        union { unsigned long long q[2]; bf16x8 v; } u;
        u.q[0] = q0[2 * kt]; u.q[1] = q0[2 * kt + 1]; a0[kt] = u.v;
        u.q[0] = q1[2 * kt]; u.q[1] = q1[2 * kt + 1]; a1[kt] = u.v;
        u.q[0] = q2[2 * kt]; u.q[1] = q2[2 * kt + 1]; a2[kt] = u.v;
        u.q[0] = q3[2 * kt]; u.q[1] = q3[2 * kt + 1]; a3[kt] = u.v;
    }
}

// DIRECT row-major publish: lane (col m16, rows 4hi..4hi+3) pairs with lane m16^1
// via shfl (r6/r8/r9/r11-proven) and scatters 2 u32 agent stores.
__device__ __forceinline__ void pub_rm(char* gslot, int m16, int hi, const float* v) {
    const int odd = m16 & 1;
    float oth[4];
#pragma unroll
    for (int j = 0; j < 4; ++j) oth[j] = __shfl_xor(v[j], 1);
#pragma unroll
    for (int k = 0; k < 2; ++k) {
        const int j = odd * 2 + k;
        const int r = hi * 4 + j;
        unsigned a = f2bf(v[j]), b = f2bf(oth[j]);
        unsigned u = odd ? (b | (a << 16)) : (a | (b << 16));
        AGST((unsigned*)(gslot + r * 32 + (m16 & ~1) * 2), u);
    }
}

// ================= POLL main: write-once slots, data-is-the-flag =================
// grid: 128 blocks; rg = bid&15, cg = bid>>4. 256 threads = 4 waves:
// wave w: tile tt = 2*cg + (w>>1), role (w&1): 0 = h-path (+ y duty), 1 = z-path.
// NO barriers, NO flags, NO drains: publishers scatter-store and move on; readers
// poll their fragments until poison-free (fresh slot per step).
__launch_bounds__(256, 1)
__global__ void twistor_poll(const float* __restrict__ x, unsigned short* __restrict__ ws,
                             float* __restrict__ y) {
    const int tid  = threadIdx.x;
    const int lane = tid & 63;
    const int w    = tid >> 6;
    const int half = w >> 1;
    const int role = w & 1;
    const int m16  = lane & 15;
    const int hi   = lane >> 4;
    const int loff = lane * 8;
    const int bid  = blockIdx.x;
    const int rg   = bid & 15;
    const int cg   = bid >> 4;
    const int tt   = cg * 2 + half;
    const int brow0 = rg * 16;
    const int n    = tt * 16 + m16;
    const float* bias = (const float*)((const char*)ws + BIAS_OFF_BYTES);
    char* simg = (char*)ws + REGION_OFF_BYTES;

    bf16x8 wA[8], wB[8], wC[8], wU[4];
    bf16x8 wO[8], wO2[8];
    bf16x8 wTZ[8];
    if (role == 0) {
        wload<8>(wA, ws + G_WH    * 65536 + tt * 4096, loff);
        wload<8>(wB, ws + G_WTAUH * 65536 + tt * 4096, loff);
        wload<8>(wC, ws + G_Z2H   * 65536 + tt * 4096, loff);
        wload<4>(wU, ws + UH + tt * 2048, loff);
        if (tt < 4) {
            wload<8>(wO,  ws + OH + tt * 4096, loff);
            wload<8>(wO2, ws + OZ + tt * 4096, loff);
        }
    } else {
        wload<8>(wA, ws + G_WZR   * 65536 + tt * 4096, loff);
        wload<8>(wB, ws + G_WZI   * 65536 + tt * 4096, loff);
        wload<8>(wC, ws + G_H2Z   * 65536 + tt * 4096, loff);
        wload<4>(wU, ws + UZ + tt * 2048, loff);
        wload<8>(wTZ, ws + G_WTAUZ * 65536 + tt * 4096, loff);
    }

    const float bthh = bias[BT_H + n],    btauh = bias[BTAU_H + n], bht = bias[BH_TOT + n];
    const float btzr = bias[BT_ZR + n],   btzi  = bias[BT_ZI + n],  btauz = bias[BTAU_Z + n];
    const float bzrt = bias[BZR_TOT + n], bzit  = bias[BZI_TOT + n];
    const float by_  = (tt < 4 && role == 0) ? bias[BY + n] : 0.f;

    float s0_[4] = {0, 0, 0, 0};
    float s1_[4] = {0, 0, 0, 0};

    for (int t = 0; t < T_; ++t) {
        bf16x8 ax[4];
        {
            const float* xrow = x + ((size_t)t * B_ + brow0 + m16) * INP_;
#pragma unroll
            for (int kt = 0; kt < 4; ++kt) ax[kt] = loadXfrag(xrow, kt * 32 + hi * 8);
        }
        const char* slotR = simg + ((size_t)t * 16 + rg) * 32768;
        char*       slotW = simg + ((size_t)(t + 1) * 16 + rg) * 32768;

        if (role == 0) {
            bf16x8 ah[8], azr[8];
            pollA2(slotR, m16, hi, ah, azr);
            const bool ydo = (tt < 4) && (t > 0);
            f32x4 a_y = {0.f, 0.f, 0.f, 0.f};
            if (ydo) { wgemm<8>(ah, wO, a_y); wgemm<8>(azr, wO2, a_y); }
            f32x4 a_th = {0.f, 0.f, 0.f, 0.f}, a_tau = {0.f, 0.f, 0.f, 0.f};
            f32x4 a_ch = {0.f, 0.f, 0.f, 0.f};
            wgemm<8>(ah,  wA, a_th);
            wgemm<8>(ah,  wB, a_tau);
            wgemm<8>(azr, wC, a_ch);
            wgemm<4>(ax,  wU, a_ch);
            if (ydo) {
#pragma unroll
                for (int j = 0; j < 4; ++j)
                    y[((size_t)(t - 1) * B_ + brow0 + hi * 4 + j) * OUT_ + n] =
                        a_y[j] + by_;
            }
            float hn[4];
#pragma unroll
            for (int j = 0; j < 4; ++j) {
                float th = fminf(fmaxf(sigmoid_fast(a_tau[j] + btauh), 0.01f), 1.0f) + 1e-6f;
                float dh = -s0_[j] + tanh_fast(a_th[j] + bthh) + a_ch[j] + bht;
                hn[j]    = s0_[j] + DT_ * dh * rcp_(th);
                s0_[j] = hn[j];
            }
            pub_rm(slotW + tt * 512, m16, hi, hn);                       // state 0 (h)
        } else {
            bf16x8 ah[8], azr[8], azi[8], aza[8];
            pollA4(slotR, m16, hi, ah, azr, azi, aza);
            f32x4 a_tzr = {0.f, 0.f, 0.f, 0.f}, a_tzi = {0.f, 0.f, 0.f, 0.f};
            f32x4 a_tz  = {0.f, 0.f, 0.f, 0.f}, a_cz  = {0.f, 0.f, 0.f, 0.f};
            wgemm<8>(azr, wA,  a_tzr);
            wgemm<8>(ah,  wC,  a_cz);
            wgemm<8>(azi, wB,  a_tzi);
            wgemm<8>(aza, wTZ, a_tz);
            wgemm<4>(ax,  wU,  a_cz);
            float zrn[4], zin[4], zan[4];
#pragma unroll
            for (int j = 0; j < 4; ++j) {
                float tz  = fminf(fmaxf(sigmoid_fast(a_tz[j] + btauz), 0.01f), 1.0f) + 1e-6f;
                float rtz = rcp_(tz);
                float dzr = -s0_[j] + tanh_fast(a_tzr[j] + btzr) + a_cz[j] + bzrt;
                float dzi = -s1_[j] + tanh_fast(a_tzi[j] + btzi) + a_cz[j] + bzit;
                zrn[j] = s0_[j] + DT_ * dzr * rtz;
                zin[j] = s1_[j] + DT_ * dzi * rtz;
                zan[j] = sqrtf(zrn[j] * zrn[j] + zin[j] * zin[j] + 1e-24f);
                s0_[j] = zrn[j]; s1_[j] = zin[j];
            }
            pub_rm(slotW + 8192  + tt * 512, m16, hi, zrn);              // state 1 (zr)
            pub_rm(slotW + 16384 + tt * 512, m16, hi, zin);              // state 2 (zi)
            pub_rm(slotW + 24576 + tt * 512, m16, hi, zan);              // state 3 (za)
        }
        // nothing else: no drain, no flag, no barrier.
    }

    // final y_{T-1} from S_T (slot T_)
    if (role == 0 && tt < 4) {
        const char* slotR = simg + ((size_t)T_ * 16 + rg) * 32768;
        bf16x8 ah[8], azr[8];
        pollA2(slotR, m16, hi, ah, azr);
        f32x4 a_y = {0.f, 0.f, 0.f, 0.f};
        wgemm<8>(ah,  wO,  a_y);
        wgemm<8>(azr, wO2, a_y);
#pragma unroll
        for (int j = 0; j < 4; ++j)
            y[((size_t)(T_ - 1) * B_ + brow0 + hi * 4 + j) * OUT_ + n] = a_y[j] + by_;
    }
}

// ================= FLAG fallback main (r13, proven 2.9ms) =================
__device__ __forceinline__ void waitflags(const unsigned* flg, int lane, unsigned tgt) {
    for (;;) {
        unsigned v = tgt;
        if (lane < 32) v = AGLD(flg + lane * 16);
        if (__all((int)(v >= tgt))) break;
        __builtin_amdgcn_s_sleep(1);
    }
}
__device__ __forceinline__ void postflag(unsigned* myflag, int lane, unsigned val) {
    asm volatile("s_waitcnt vmcnt(0)" ::: "memory");
    if (lane == 0) AGST(myflag, val);
}

__launch_bounds__(256, 1)
__global__ void twistor_flag(const float* __restrict__ x, unsigned short* __restrict__ ws,
                             float* __restrict__ y) {
    const int tid  = threadIdx.x;
    const int lane = tid & 63;
    const int w    = tid >> 6;
    const int half = w >> 1;
    const int role = w & 1;
    const int m16  = lane & 15;
    const int hi   = lane >> 4;
    const int loff = lane * 8;
    const int bid  = blockIdx.x;
    const int rg   = bid & 15;
    const int cg   = bid >> 4;
    const int tt   = cg * 2 + half;
    const int brow0 = rg * 16;
    const int n    = tt * 16 + m16;
    const float* bias = (const float*)((const char*)ws + BIAS_OFF_BYTES);
    unsigned* flg    = (unsigned*)((char*)ws + REGION_OFF_BYTES) + rg * 512;
    unsigned* myflag = flg + (tt * 2 + role) * 16;
    char* simg = (char*)ws + REGION_OFF_BYTES + 32768;

    bf16x8 wA[8], wB[8], wC[8], wU[4];
    bf16x8 wO[8], wO2[8];
    bf16x8 wTZ[8];
    if (role == 0) {
        wload<8>(wA, ws + G_WH    * 65536 + tt * 4096, loff);
        wload<8>(wB, ws + G_WTAUH * 65536 + tt * 4096, loff);
        wload<8>(wC, ws + G_Z2H   * 65536 + tt * 4096, loff);
        wload<4>(wU, ws + UH + tt * 2048, loff);
        if (tt < 4) {
            wload<8>(wO,  ws + OH + tt * 4096, loff);
            wload<8>(wO2, ws + OZ + tt * 4096, loff);
        }
    } else {
        wload<8>(wA, ws + G_WZR   * 65536 + tt * 4096, loff);
        wload<8>(wB, ws + G_WZI   * 65536 + tt * 4096, loff);
        wload<8>(wC, ws + G_H2Z   * 65536 + tt * 4096, loff);
        wload<4>(wU, ws + UZ + tt * 2048, loff);
        wload<8>(wTZ, ws + G_WTAUZ * 65536 + tt * 4096, loff);
    }

    const float bthh = bias[BT_H + n],    btauh = bias[BTAU_H + n], bht = bias[BH_TOT + n];
    const float btzr = bias[BT_ZR + n],   btzi  = bias[BT_ZI + n],  btauz = bias[BTAU_Z + n];
    const float bzrt = bias[BZR_TOT + n], bzit  = bias[BZI_TOT + n];
    const float by_  = (tt < 4 && role == 0) ? bias[BY + n] : 0.f;

    float s0_[4] = {0, 0, 0, 0};
    float s1_[4] = {0, 0, 0, 0};

    for (int t = 0; t < T_; ++t) {
        bf16x8 ax[4];
        {
            const float* xrow = x + ((size_t)t * B_ + brow0 + m16) * INP_;
#pragma unroll
            for (int kt = 0; kt < 4; ++kt) ax[kt] = loadXfrag(xrow, kt * 32 + hi * 8);
        }
        if (t > 0) waitflags(flg, lane, (unsigned)t);

        const char* imgR = simg + (size_t)((t & 1) * 16 + rg) * 32768;
        char*       imgW = simg + (size_t)(((t + 1) & 1) * 16 + rg) * 32768;

        bf16x8 ah[8], azr[8];
        loadAimg(imgR,        m16, hi, ah);
        loadAimg(imgR + 8192, m16, hi, azr);

        if (role == 0) {
            const bool ydo = (tt < 4) && (t > 0);
            f32x4 a_y = {0.f, 0.f, 0.f, 0.f};
            if (ydo) { wgemm<8>(ah, wO, a_y); wgemm<8>(azr, wO2, a_y); }
            f32x4 a_th = {0.f, 0.f, 0.f, 0.f}, a_tau = {0.f, 0.f, 0.f, 0.f};
            f32x4 a_ch = {0.f, 0.f, 0.f, 0.f};
            wgemm<8>(ah,  wA, a_th);
            wgemm<8>(ah,  wB, a_tau);
            wgemm<8>(azr, wC, a_ch);
            wgemm<4>(ax,  wU, a_ch);
            if (ydo) {
#pragma unroll
                for (int j = 0; j < 4; ++j)
                    y[((size_t)(t - 1) * B_ + brow0 + hi * 4 + j) * OUT_ + n] =
                        a_y[j] + by_;
            }
            float hn[4];
#pragma unroll
            for (int j = 0; j < 4; ++j) {
                float th = fminf(fmaxf(sigmoid_fast(a_tau[j] + btauh), 0.01f), 1.0f) + 1e-6f;
                float dh = -s0_[j] + tanh_fast(a_th[j] + bthh) + a_ch[j] + bht;
                hn[j]    = s0_[j] + DT_ * dh * rcp_(th);
                s0_[j] = hn[j];
            }
            pub_rm(imgW + tt * 512, m16, hi, hn);
        } else {
            bf16x8 azi[8], aza[8];
            loadAimg(imgR + 16384, m16, hi, azi);
            loadAimg(imgR + 24576, m16, hi, aza);
            f32x4 a_tzr = {0.f, 0.f, 0.f, 0.f}, a_tzi = {0.f, 0.f, 0.f, 0.f};
            f32x4 a_tz  = {0.f, 0.f, 0.f, 0.f}, a_cz  = {0.f, 0.f, 0.f, 0.f};
            wgemm<8>(azr, wA,  a_tzr);
            wgemm<8>(ah,  wC,  a_cz);
            wgemm<8>(azi, wB,  a_tzi);
            wgemm<8>(aza, wTZ, a_tz);
            wgemm<4>(ax,  wU,  a_cz);
            float zrn[4], zin[4], zan[4];
#pragma unroll
            for (int j = 0; j < 4; ++j) {
                float tz  = fminf(fmaxf(sigmoid_fast(a_tz[j] + btauz), 0.01f), 1.0f) + 1e-6f;
                float rtz = rcp_(tz);
                float dzr = -s0_[j] + tanh_fast(a_tzr[j] + btzr) + a_cz[j] + bzrt;
                float dzi = -s1_[j] + tanh_fast(a_tzi[j] + btzi) + a_cz[j] + bzit;
                zrn[j] = s0_[j] + DT_ * dzr * rtz;
                zin[j] = s1_[j] + DT_ * dzi * rtz;
                zan[j] = sqrtf(zrn[j] * zrn[j] + zin[j] * zin[j] + 1e-24f);
                s0_[j] = zrn[j]; s1_[j] = zin[j];
            }
            pub_rm(imgW + 8192  + tt * 512, m16, hi, zrn);
            pub_rm(imgW + 16384 + tt * 512, m16, hi, zin);
            pub_rm(imgW + 24576 + tt * 512, m16, hi, zan);
        }
        postflag(myflag, lane, (unsigned)(t + 1));
    }

    if (role == 0 && tt < 4) {
        waitflags(flg, lane, (unsigned)T_);
        const char* imgR = simg + (size_t)((T_ & 1) * 16 + rg) * 32768;
        bf16x8 ah[8], azr[8];
        loadAimg(imgR,        m16, hi, ah);
        loadAimg(imgR + 8192, m16, hi, azr);
        f32x4 a_y = {0.f, 0.f, 0.f, 0.f};
        wgemm<8>(ah,  wO,  a_y);
        wgemm<8>(azr, wO2, a_y);
#pragma unroll
        for (int j = 0; j < 4; ++j)
            y[((size_t)(T_ - 1) * B_ + brow0 + hi * 4 + j) * OUT_ + n] = a_y[j] + by_;
    }
}

extern "C" void kernel_launch(void* const* d_in, const int* in_sizes, int n_in,
                              void* d_out, int out_size, void* d_ws, size_t ws_size,
                              hipStream_t stream) {
    const float* x = (const float*)d_in[0];
    unsigned short* ws = (unsigned short*)d_ws;
    float* bias = (float*)((char*)d_ws + BIAS_OFF_BYTES);

    prep_weights<<<(NW_TOTAL / 8 + 255) / 256, 256, 0, stream>>>(
        (const float*)d_in[1],  /* W_h_w */
        (const float*)d_in[5],  /* W_tau_h_w */
        (const float*)d_in[8],  /* W_z_real_w */
        (const float*)d_in[10], /* W_z_imag_w */
        (const float*)d_in[14], /* W_tau_z_w */
        (const float*)d_in[18], /* h2z_w */
        (const float*)d_in[20], /* z2h_w */
        (const float*)d_in[3],  /* U_h_w */
        (const float*)d_in[12], /* U_z_w */
        (const float*)d_in[22], /* out_h_w */
        (const float*)d_in[24], /* out_z_w */
        ws);
    prep_bias<<<1, 256, 0, stream>>>(
        (const float*)d_in[2],  /* W_h_b */
        (const float*)d_in[6],  /* W_tau_h_b */
        (const float*)d_in[4],  /* U_h_b */
        (const float*)d_in[7],  /* b_h */
        (const float*)d_in[21], /* z2h_b */
        (const float*)d_in[9],  /* W_z_real_b */
        (const float*)d_in[11], /* W_z_imag_b */
        (const float*)d_in[15], /* W_tau_z_b */
        (const float*)d_in[13], /* U_z_b */
        (const float*)d_in[16], /* b_z_real */
        (const float*)d_in[17], /* b_z_imag */
        (const float*)d_in[19], /* h2z_b */
        (const float*)d_in[23], /* out_h_b */
        (const float*)d_in[25], /* out_z_b */
        bias);

    const size_t pollNeed = (size_t)REGION_OFF_BYTES + 513ull * 16 * 32768;
    if (ws_size >= pollNeed) {
        prep_poison<<<8192, 512, 0, stream>>>(
            (unsigned long long*)((char*)d_ws + REGION_OFF_BYTES));
        twistor_poll<<<128, 256, 0, stream>>>(x, ws, (float*)d_out);
    } else {
        prep_zero<<<264, 512, 0, stream>>>(
            (unsigned long long*)((char*)d_ws + REGION_OFF_BYTES));
        twistor_flag<<<128, 256, 0, stream>>>(x, ws, (float*)d_out);
    }
}